// Round 1
// baseline (905.335 us; speedup 1.0000x reference)
//
#include <hip/hip_runtime.h>
#include <hip/hip_bf16.h>

// -------------------------------------------------------------------------
// SAGEConv encoder, 2 layers, mean aggregation, fused bias + L2 normalize.
// Strategy: build CSR once (shared by both layers), wave-per-node gather
// aggregation, persistent-block fused GEMV (K=256 combined weights in LDS).
// -------------------------------------------------------------------------

__device__ __forceinline__ float rdlane(float v, int lane) {
    return __int_as_float(__builtin_amdgcn_readlane(__float_as_int(v), lane));
}

// ---- edge_index dtype detection (int32 vs int64) -------------------------
__global__ void detect_kernel(const int* __restrict__ ei, int* __restrict__ flag) {
    if (threadIdx.x == 0 && blockIdx.x == 0) {
        int z = 1;
        for (int j = 0; j < 64; ++j)
            if (ei[2 * j + 1] != 0) { z = 0; break; }
        *flag = z;  // 1 -> data is int64, 0 -> int32
    }
}

__device__ __forceinline__ int load_idx(const void* ei, int is64, size_t i) {
    return is64 ? (int)((const long long*)ei)[i] : ((const int*)ei)[i];
}

// ---- degree histogram ----------------------------------------------------
__global__ void hist_kernel(const void* __restrict__ ei, const int* __restrict__ flagp,
                            int* __restrict__ deg, int E) {
    const int i = blockIdx.x * 256 + threadIdx.x;
    if (i >= E) return;
    const int is64 = *flagp;
    const int d = load_idx(ei, is64, (size_t)E + i);
    atomicAdd(&deg[d], 1);
}

// ---- 3-kernel exclusive scan over deg[] ----------------------------------
__global__ void scan1_kernel(const int* __restrict__ deg, int* __restrict__ partial,
                             int* __restrict__ blksum, int n) {
    __shared__ int wtot[4];
    const int tid = threadIdx.x, lane = tid & 63, wid = tid >> 6;
    const int i = blockIdx.x * 256 + tid;
    int v = (i < n) ? deg[i] : 0;
    int incl = v;
    for (int d = 1; d < 64; d <<= 1) {
        int up = __shfl_up(incl, d, 64);
        if (lane >= d) incl += up;
    }
    if (lane == 63) wtot[wid] = incl;
    __syncthreads();
    int woff = 0;
    for (int w = 0; w < wid; ++w) woff += wtot[w];
    if (i < n) partial[i] = woff + incl - v;       // block-local exclusive
    if (tid == 255) blksum[blockIdx.x] = woff + incl;
}

__global__ void scan2_kernel(const int* __restrict__ blksum, int* __restrict__ blkoff, int nb) {
    __shared__ int wtot[8];
    const int tid = threadIdx.x, lane = tid & 63, wid = tid >> 6;
    int v = (tid < nb) ? blksum[tid] : 0;
    int incl = v;
    for (int d = 1; d < 64; d <<= 1) {
        int up = __shfl_up(incl, d, 64);
        if (lane >= d) incl += up;
    }
    if (lane == 63) wtot[wid] = incl;
    __syncthreads();
    int woff = 0;
    for (int w = 0; w < wid; ++w) woff += wtot[w];
    if (tid < nb) blkoff[tid] = woff + incl - v;
    if (tid == nb - 1) blkoff[nb] = woff + incl;   // total = E
}

__global__ void scan3_kernel(int* __restrict__ rs /*==partial*/, const int* __restrict__ blkoff,
                             const int* __restrict__ deg, int* __restrict__ cursor,
                             float* __restrict__ invd, int n, int nb) {
    const int i = blockIdx.x * 256 + threadIdx.x;
    if (i < n) {
        const int v = rs[i] + blkoff[blockIdx.x];
        rs[i] = v;
        cursor[i] = v;
        const int d = deg[i];
        invd[i] = 1.0f / (float)(d > 1 ? d : 1);
    }
    if (i == 0) rs[n] = blkoff[nb];
}

// ---- CSR fill ------------------------------------------------------------
__global__ void fill_kernel(const void* __restrict__ ei, const int* __restrict__ flagp,
                            int* __restrict__ cursor, int* __restrict__ csr, int E) {
    const int i = blockIdx.x * 256 + threadIdx.x;
    if (i >= E) return;
    const int is64 = *flagp;
    const int s = load_idx(ei, is64, (size_t)i);
    const int d = load_idx(ei, is64, (size_t)E + i);
    const int pos = atomicAdd(&cursor[d], 1);
    csr[pos] = s;
}

// ---- mean aggregation: one wave per destination node ---------------------
__global__ void aggregate_kernel(const float* __restrict__ feat, const int* __restrict__ csr,
                                 const int* __restrict__ rs, const float* __restrict__ invd,
                                 float* __restrict__ aggout, int n) {
    const int wid = threadIdx.x >> 6, lane = threadIdx.x & 63;
    const int node = blockIdx.x * 4 + wid;
    if (node >= n) return;
    const int s = rs[node], e = rs[node + 1];
    float ax = 0.f, ay = 0.f;
    for (int q = s; q < e; ++q) {
        const int src = csr[q];                     // wave-uniform -> s_load
        const float2 v = *(const float2*)(feat + (size_t)src * 128 + 2 * lane);
        ax += v.x; ay += v.y;
    }
    const float iv = invd[node];
    *(float2*)(aggout + (size_t)node * 128 + 2 * lane) = make_float2(ax * iv, ay * iv);
}

// ---- fused GEMV (K=256) + bias + L2 normalize ----------------------------
// out[r] = normalize( agg[r] @ Wl^T + b + x[r] @ Wr^T )
// Combined input c[k] = agg[r][k] (k<128) | x[r][k-128] (k>=128).
// Lane l holds c[4l..4l+3] in one float4; broadcast via v_readlane.
// Wt[k][ch] staged once per persistent block in 128 KiB LDS.
__global__ __launch_bounds__(512) void sage_gemm_kernel(
    const float* __restrict__ agg, const float* __restrict__ xin,
    const float* __restrict__ Wl, const float* __restrict__ bias,
    const float* __restrict__ Wr, float* __restrict__ out, int n) {
    __shared__ float Wt[256][128];
    for (int i = threadIdx.x; i < 128 * 128; i += 512) {
        const int ch = i >> 7, k = i & 127;
        Wt[k][ch]       = Wl[i];   // Wl[ch][k]
        Wt[k + 128][ch] = Wr[i];   // Wr[ch][k-128]
    }
    __syncthreads();

    const int wid = threadIdx.x >> 6, lane = threadIdx.x & 63;
    const float2 bv = *(const float2*)(bias + 2 * lane);
    const int npairs = (n + 1) >> 1;

    for (int p = blockIdx.x * 8 + wid; p < npairs; p += gridDim.x * 8) {
        const int r0 = 2 * p;
        const int r1v = r0 + 1;
        const bool has1 = (r1v < n);
        const int r1 = has1 ? r1v : r0;

        union { float4 v; float f[4]; } a0, a1;
        const float* p0 = (lane < 32) ? (agg + (size_t)r0 * 128 + 4 * lane)
                                      : (xin + (size_t)r0 * 128 + 4 * (lane - 32));
        const float* p1 = (lane < 32) ? (agg + (size_t)r1 * 128 + 4 * lane)
                                      : (xin + (size_t)r1 * 128 + 4 * (lane - 32));
        a0.v = *(const float4*)p0;
        a1.v = *(const float4*)p1;

        float2 acc0 = bv, acc1 = bv;
#pragma unroll 8
        for (int k4 = 0; k4 < 64; ++k4) {
#pragma unroll
            for (int j = 0; j < 4; ++j) {
                const float2 w = *(const float2*)&Wt[4 * k4 + j][2 * lane];
                const float s0 = rdlane(a0.f[j], k4);
                const float s1 = rdlane(a1.f[j], k4);
                acc0.x = fmaf(s0, w.x, acc0.x);
                acc0.y = fmaf(s0, w.y, acc0.y);
                acc1.x = fmaf(s1, w.x, acc1.x);
                acc1.y = fmaf(s1, w.y, acc1.y);
            }
        }

        float ss0 = fmaf(acc0.x, acc0.x, acc0.y * acc0.y);
        float ss1 = fmaf(acc1.x, acc1.x, acc1.y * acc1.y);
        for (int d = 1; d < 64; d <<= 1) {
            ss0 += __shfl_xor(ss0, d, 64);
            ss1 += __shfl_xor(ss1, d, 64);
        }
        const float sc0 = 1.0f / fmaxf(sqrtf(ss0), 1e-12f);
        const float sc1 = 1.0f / fmaxf(sqrtf(ss1), 1e-12f);

        *(float2*)(out + (size_t)r0 * 128 + 2 * lane) =
            make_float2(acc0.x * sc0, acc0.y * sc0);
        if (has1)
            *(float2*)(out + (size_t)r1 * 128 + 2 * lane) =
                make_float2(acc1.x * sc1, acc1.y * sc1);
    }
}

// -------------------------------------------------------------------------
extern "C" void kernel_launch(void* const* d_in, const int* in_sizes, int n_in,
                              void* d_out, int out_size, void* d_ws, size_t ws_size,
                              hipStream_t stream) {
    const float* x   = (const float*)d_in[0];
    const void*  ei  = d_in[1];
    const float* Wl1 = (const float*)d_in[2];
    const float* bl1 = (const float*)d_in[3];
    const float* Wr1 = (const float*)d_in[4];
    const float* Wl2 = (const float*)d_in[5];
    const float* bl2 = (const float*)d_in[6];
    const float* Wr2 = (const float*)d_in[7];
    float* out = (float*)d_out;

    const int N = in_sizes[0] / 128;
    const int E = in_sizes[1] / 2;

    char* wsb = (char*)d_ws;
    size_t off = 0;
    auto alloc = [&](size_t bytes) -> void* {
        void* p = (void*)(wsb + off);
        off += bytes;
        off = (off + 255) & ~(size_t)255;
        return p;
    };

    int*   deg    = (int*)alloc(4 * (size_t)N);
    int*   rs     = (int*)alloc(4 * (size_t)(N + 1));   // also scan partial
    int*   cursor = (int*)alloc(4 * (size_t)N);
    float* invd   = (float*)alloc(4 * (size_t)N);
    int*   blksum = (int*)alloc(4 * 2048);
    int*   blkoff = (int*)alloc(4 * 2049);
    int*   flag   = (int*)alloc(256);
    int*   csr    = (int*)alloc(4 * (size_t)E);
    float* aggb   = (float*)alloc((size_t)N * 128 * 4);

    const int eb = (E + 255) / 256;       // edge-parallel blocks
    const int nb = (N + 255) / 256;       // node-parallel blocks (scan blocking)

    detect_kernel<<<1, 64, 0, stream>>>((const int*)ei, flag);
    hipMemsetAsync(deg, 0, 4 * (size_t)N, stream);
    hist_kernel<<<eb, 256, 0, stream>>>(ei, flag, deg, E);
    scan1_kernel<<<nb, 256, 0, stream>>>(deg, rs, blksum, N);
    scan2_kernel<<<1, 512, 0, stream>>>(blksum, blkoff, nb);
    scan3_kernel<<<nb, 256, 0, stream>>>(rs, blkoff, deg, cursor, invd, N, nb);
    fill_kernel<<<eb, 256, 0, stream>>>(ei, flag, cursor, csr, E);

    const int ab = (N + 3) / 4;           // aggregation: 4 waves/block, 1 node/wave

    // Layer 1: h1 -> d_out
    aggregate_kernel<<<ab, 256, 0, stream>>>(x, csr, rs, invd, aggb, N);
    sage_gemm_kernel<<<256, 512, 0, stream>>>(aggb, x, Wl1, bl1, Wr1, out, N);

    // Layer 2: in-place on d_out
    aggregate_kernel<<<ab, 256, 0, stream>>>(out, csr, rs, invd, aggb, N);
    sage_gemm_kernel<<<256, 512, 0, stream>>>(aggb, out, Wl2, bl2, Wr2, out, N);
}

// Round 2
// 475.545 us; speedup vs baseline: 1.9038x; 1.9038x over previous
//
#include <hip/hip_runtime.h>
#include <hip/hip_bf16.h>

// -------------------------------------------------------------------------
// SAGEConv encoder, 2 layers.
// Key identity: mean_agg(x) @ Wl^T == mean_agg(x @ Wl^T)  (linearity).
// Per layer:
//   1) MFMA GEMM: y_l = x@Wl^T (bf16 out), y_r = x@Wr^T (bf16 out)
//   2) fused gather-mean(y_l) + y_r + bias + L2-normalize
// CSR built once, shared by both layers.
// -------------------------------------------------------------------------

typedef __attribute__((ext_vector_type(8))) short bf16x8;
typedef __attribute__((ext_vector_type(4))) float f32x4;

__device__ __forceinline__ ushort f2bf(float f) {
    uint u = __float_as_uint(f);
    uint r = (u + 0x7FFFu + ((u >> 16) & 1u)) >> 16;   // RNE
    return (ushort)r;
}
__device__ __forceinline__ float bflo(uint u) { return __uint_as_float(u << 16); }
__device__ __forceinline__ float bfhi(uint u) { return __uint_as_float(u & 0xFFFF0000u); }

// ---- edge_index dtype detection (int32 vs int64) -------------------------
__global__ void detect_kernel(const int* __restrict__ ei, int* __restrict__ flag) {
    if (threadIdx.x == 0 && blockIdx.x == 0) {
        int z = 1;
        for (int j = 0; j < 64; ++j)
            if (ei[2 * j + 1] != 0) { z = 0; break; }
        *flag = z;  // 1 -> int64, 0 -> int32
    }
}

__device__ __forceinline__ int load_idx(const void* ei, int is64, size_t i) {
    return is64 ? (int)((const long long*)ei)[i] : ((const int*)ei)[i];
}

// ---- degree histogram ----------------------------------------------------
__global__ void hist_kernel(const void* __restrict__ ei, const int* __restrict__ flagp,
                            int* __restrict__ deg, int E) {
    const int i = blockIdx.x * 256 + threadIdx.x;
    if (i >= E) return;
    const int is64 = *flagp;
    const int d = load_idx(ei, is64, (size_t)E + i);
    atomicAdd(&deg[d], 1);
}

// ---- 3-kernel exclusive scan over deg[] ----------------------------------
__global__ void scan1_kernel(const int* __restrict__ deg, int* __restrict__ partial,
                             int* __restrict__ blksum, int n) {
    __shared__ int wtot[4];
    const int tid = threadIdx.x, lane = tid & 63, wid = tid >> 6;
    const int i = blockIdx.x * 256 + tid;
    int v = (i < n) ? deg[i] : 0;
    int incl = v;
    for (int d = 1; d < 64; d <<= 1) {
        int up = __shfl_up(incl, d, 64);
        if (lane >= d) incl += up;
    }
    if (lane == 63) wtot[wid] = incl;
    __syncthreads();
    int woff = 0;
    for (int w = 0; w < wid; ++w) woff += wtot[w];
    if (i < n) partial[i] = woff + incl - v;
    if (tid == 255) blksum[blockIdx.x] = woff + incl;
}

__global__ void scan2_kernel(const int* __restrict__ blksum, int* __restrict__ blkoff, int nb) {
    __shared__ int wtot[8];
    const int tid = threadIdx.x, lane = tid & 63, wid = tid >> 6;
    int v = (tid < nb) ? blksum[tid] : 0;
    int incl = v;
    for (int d = 1; d < 64; d <<= 1) {
        int up = __shfl_up(incl, d, 64);
        if (lane >= d) incl += up;
    }
    if (lane == 63) wtot[wid] = incl;
    __syncthreads();
    int woff = 0;
    for (int w = 0; w < wid; ++w) woff += wtot[w];
    if (tid < nb) blkoff[tid] = woff + incl - v;
    if (tid == nb - 1) blkoff[nb] = woff + incl;
}

__global__ void scan3_kernel(int* __restrict__ rs, const int* __restrict__ blkoff,
                             const int* __restrict__ deg, int* __restrict__ cursor,
                             float* __restrict__ invd, int n, int nb) {
    const int i = blockIdx.x * 256 + threadIdx.x;
    if (i < n) {
        const int v = rs[i] + blkoff[blockIdx.x];
        rs[i] = v;
        cursor[i] = v;
        const int d = deg[i];
        invd[i] = 1.0f / (float)(d > 1 ? d : 1);
    }
    if (i == 0) rs[n] = blkoff[nb];
}

// ---- CSR fill ------------------------------------------------------------
__global__ void fill_kernel(const void* __restrict__ ei, const int* __restrict__ flagp,
                            int* __restrict__ cursor, int* __restrict__ csr, int E) {
    const int i = blockIdx.x * 256 + threadIdx.x;
    if (i >= E) return;
    const int is64 = *flagp;
    const int s = load_idx(ei, is64, (size_t)i);
    const int d = load_idx(ei, is64, (size_t)E + i);
    const int pos = atomicAdd(&cursor[d], 1);
    csr[pos] = s;
}

// ---- f32 -> bf16 conversion (8 elems/thread) -----------------------------
__global__ void convert_bf16_kernel(const float* __restrict__ in, ushort* __restrict__ out,
                                    long total8) {
    const long i = (long)blockIdx.x * 256 + threadIdx.x;
    if (i >= total8) return;
    const float4 a = ((const float4*)in)[2 * i];
    const float4 b = ((const float4*)in)[2 * i + 1];
    uint4 o;
    o.x = (uint)f2bf(a.x) | ((uint)f2bf(a.y) << 16);
    o.y = (uint)f2bf(a.z) | ((uint)f2bf(a.w) << 16);
    o.z = (uint)f2bf(b.x) | ((uint)f2bf(b.y) << 16);
    o.w = (uint)f2bf(b.z) | ((uint)f2bf(b.w) << 16);
    ((uint4*)out)[i] = o;
}

// ---- pack W into MFMA B-fragment layout ----------------------------------
// B-frag for mfma_f32_16x16x32_bf16: lane l holds B[k=(l>>4)*8+j][col=l&15].
// Packed: Wp[layer][(s*16+t)*64 + lane][j], s=ktile(4), t=ntile(16).
// Logical B[k][c]: c<128 -> Wl[c][k], c>=128 -> Wr[c-128][k].
__global__ void pack_w_kernel(const float* __restrict__ Wl1, const float* __restrict__ Wr1,
                              const float* __restrict__ Wl2, const float* __restrict__ Wr2,
                              ushort* __restrict__ Wp) {
    const int gtid = blockIdx.x * 256 + threadIdx.x;   // [0, 8192)
    if (gtid >= 8192) return;
    const int layer = gtid >> 12;
    const int c16   = gtid & 4095;
    const int s     = c16 >> 10;
    const int t     = (c16 >> 6) & 15;
    const int lane  = c16 & 63;
    const int c     = t * 16 + (lane & 15);
    const int kbase = s * 32 + (lane >> 4) * 8;
    const float* Wl = layer ? Wl2 : Wl1;
    const float* Wr = layer ? Wr2 : Wr1;
    const float* src = (c < 128) ? (Wl + c * 128 + kbase) : (Wr + (c - 128) * 128 + kbase);
    ushort* dst = Wp + (size_t)layer * 32768 + (size_t)c16 * 8;
#pragma unroll
    for (int j = 0; j < 8; ++j) dst[j] = f2bf(src[j]);
}

// ---- MFMA GEMM: [n][128]bf16 @ W[256][128]^T -> yl[n][128], yr[n][128] ---
// Persistent blocks, W fragments staged once in 64KB LDS.
// Each wave: 16 rows x 256 cols; A-frags loaded directly global->reg.
__global__ __launch_bounds__(256) void sage_mfma_gemm(
    const ushort* __restrict__ A, const ushort* __restrict__ Wp,
    ushort* __restrict__ yl, ushort* __restrict__ yr, int n, int mtiles) {
    __shared__ ushort Wlds[32768];
    for (int i = threadIdx.x; i < 4096; i += 256)
        *(bf16x8*)&Wlds[(size_t)i * 8] = *(const bf16x8*)&Wp[(size_t)i * 8];
    __syncthreads();

    const int wid = threadIdx.x >> 6, lane = threadIdx.x & 63;
    const int koff = (lane >> 4) * 8;      // element offset within row
    const int rsub = lane & 15;

    int mt = blockIdx.x;
    if (mt >= mtiles) return;

    // prefetch first A tile
    bf16x8 a_cur[4], a_nxt[4];
    {
        int arow = mt * 64 + wid * 16 + rsub;
        if (arow >= n) arow = 0;
        const ushort* ap = A + ((size_t)arow << 7) + koff;
#pragma unroll
        for (int s = 0; s < 4; ++s) a_cur[s] = *(const bf16x8*)(ap + s * 32);
    }

    while (true) {
        const int mtn = mt + gridDim.x;
        if (mtn < mtiles) {
            int arow = mtn * 64 + wid * 16 + rsub;
            if (arow >= n) arow = 0;
            const ushort* ap = A + ((size_t)arow << 7) + koff;
#pragma unroll
            for (int s = 0; s < 4; ++s) a_nxt[s] = *(const bf16x8*)(ap + s * 32);
        }

        f32x4 acc[16];
        const f32x4 zero = {0.f, 0.f, 0.f, 0.f};
#pragma unroll
        for (int t = 0; t < 16; ++t) acc[t] = zero;

#pragma unroll
        for (int s = 0; s < 4; ++s) {
            const bf16x8 as = a_cur[s];
#pragma unroll
            for (int t = 0; t < 16; ++t) {
                const bf16x8 b = *(const bf16x8*)&Wlds[(size_t)((s * 16 + t) * 64 + lane) * 8];
                acc[t] = __builtin_amdgcn_mfma_f32_16x16x32_bf16(as, b, acc[t], 0, 0, 0);
            }
        }

        // epilogue: C/D layout col=lane&15, row=(lane>>4)*4+reg
        const int rowb = mt * 64 + wid * 16 + (lane >> 4) * 4;
#pragma unroll
        for (int t = 0; t < 16; ++t) {
            ushort* dst = (t < 8) ? yl : yr;
            const int col = (t & 7) * 16 + (lane & 15);
#pragma unroll
            for (int r = 0; r < 4; ++r) {
                const int row = rowb + r;
                if (row < n) dst[((size_t)row << 7) + col] = f2bf(acc[t][r]);
            }
        }

        if (mtn >= mtiles) break;
        mt = mtn;
#pragma unroll
        for (int s = 0; s < 4; ++s) a_cur[s] = a_nxt[s];
    }
}

// ---- fused gather-mean + y_r + bias + L2-normalize -----------------------
// One wave per destination node; lane handles channels 2l, 2l+1.
template <int OUTF32>
__global__ void aggregate_norm_kernel(const ushort* __restrict__ yl, const ushort* __restrict__ yr,
                                      const float* __restrict__ bias, const int* __restrict__ csr,
                                      const int* __restrict__ rs, const float* __restrict__ invd,
                                      void* __restrict__ outp, int n) {
    const int wid = threadIdx.x >> 6, lane = threadIdx.x & 63;
    const int node = blockIdx.x * 4 + wid;
    if (node >= n) return;
    const int s = rs[node], e = rs[node + 1];

    float ax = 0.f, ay = 0.f;
    int q = s;
    for (; q + 2 <= e; q += 2) {
        const int s0 = csr[q], s1 = csr[q + 1];
        const uint u0 = *(const uint*)(yl + ((size_t)s0 << 7) + 2 * lane);
        const uint u1 = *(const uint*)(yl + ((size_t)s1 << 7) + 2 * lane);
        ax += bflo(u0) + bflo(u1);
        ay += bfhi(u0) + bfhi(u1);
    }
    if (q < e) {
        const int s0 = csr[q];
        const uint u0 = *(const uint*)(yl + ((size_t)s0 << 7) + 2 * lane);
        ax += bflo(u0);
        ay += bfhi(u0);
    }

    const float iv = invd[node];
    const uint ur = *(const uint*)(yr + ((size_t)node << 7) + 2 * lane);
    const float2 b2 = *(const float2*)(bias + 2 * lane);
    float vx = fmaf(ax, iv, bflo(ur) + b2.x);
    float vy = fmaf(ay, iv, bfhi(ur) + b2.y);

    float ss = fmaf(vx, vx, vy * vy);
    for (int d = 1; d < 64; d <<= 1) ss += __shfl_xor(ss, d, 64);
    const float sc = 1.0f / fmaxf(sqrtf(ss), 1e-12f);
    vx *= sc; vy *= sc;

    if (OUTF32) {
        ((float2*)outp)[((size_t)node << 6) + lane] = make_float2(vx, vy);
    } else {
        const uint o = (uint)f2bf(vx) | ((uint)f2bf(vy) << 16);
        ((uint*)outp)[((size_t)node << 6) + lane] = o;
    }
}

// -------------------------------------------------------------------------
extern "C" void kernel_launch(void* const* d_in, const int* in_sizes, int n_in,
                              void* d_out, int out_size, void* d_ws, size_t ws_size,
                              hipStream_t stream) {
    const float* x   = (const float*)d_in[0];
    const void*  ei  = d_in[1];
    const float* Wl1 = (const float*)d_in[2];
    const float* bl1 = (const float*)d_in[3];
    const float* Wr1 = (const float*)d_in[4];
    const float* Wl2 = (const float*)d_in[5];
    const float* bl2 = (const float*)d_in[6];
    const float* Wr2 = (const float*)d_in[7];
    float* out = (float*)d_out;

    const int N = in_sizes[0] / 128;
    const int E = in_sizes[1] / 2;

    char* wsb = (char*)d_ws;
    size_t off = 0;
    auto alloc = [&](size_t bytes) -> void* {
        void* p = (void*)(wsb + off);
        off += bytes;
        off = (off + 255) & ~(size_t)255;
        return p;
    };

    int*    deg    = (int*)alloc(4 * (size_t)N);
    int*    rs     = (int*)alloc(4 * (size_t)(N + 1));
    int*    cursor = (int*)alloc(4 * (size_t)N);
    float*  invd   = (float*)alloc(4 * (size_t)N);
    int*    blksum = (int*)alloc(4 * 2048);
    int*    blkoff = (int*)alloc(4 * 2049);
    int*    flag   = (int*)alloc(256);
    int*    csr    = (int*)alloc(4 * (size_t)E);
    ushort* xb     = (ushort*)alloc((size_t)N * 128 * 2);  // x bf16, reused as h1
    ushort* yl     = (ushort*)alloc((size_t)N * 128 * 2);
    ushort* yr     = (ushort*)alloc((size_t)N * 128 * 2);
    ushort* Wp     = (ushort*)alloc(2 * 32768 * 2);

    const int eb = (E + 255) / 256;
    const int nb = (N + 255) / 256;
    const int ab = (N + 3) / 4;
    const int mtiles = (N + 63) / 64;
    const long total8 = (long)N * 128 / 8;
    const int cb = (int)((total8 + 255) / 256);

    // CSR build (shared by both layers)
    detect_kernel<<<1, 64, 0, stream>>>((const int*)ei, flag);
    hipMemsetAsync(deg, 0, 4 * (size_t)N, stream);
    hist_kernel<<<eb, 256, 0, stream>>>(ei, flag, deg, E);
    scan1_kernel<<<nb, 256, 0, stream>>>(deg, rs, blksum, N);
    scan2_kernel<<<1, 512, 0, stream>>>(blksum, blkoff, nb);
    scan3_kernel<<<nb, 256, 0, stream>>>(rs, blkoff, deg, cursor, invd, N, nb);
    fill_kernel<<<eb, 256, 0, stream>>>(ei, flag, cursor, csr, E);

    // weight packing + x conversion
    pack_w_kernel<<<32, 256, 0, stream>>>(Wl1, Wr1, Wl2, Wr2, Wp);
    convert_bf16_kernel<<<cb, 256, 0, stream>>>(x, xb, total8);

    // Layer 1: gemm -> aggregate (h1 bf16 into xb, safe: gemm1 done with xb)
    sage_mfma_gemm<<<512, 256, 0, stream>>>(xb, Wp, yl, yr, N, mtiles);
    aggregate_norm_kernel<0><<<ab, 256, 0, stream>>>(yl, yr, bl1, csr, rs, invd, xb, N);

    // Layer 2: gemm on h1 -> aggregate -> f32 d_out
    sage_mfma_gemm<<<512, 256, 0, stream>>>(xb, Wp + 32768, yl, yr, N, mtiles);
    aggregate_norm_kernel<1><<<ab, 256, 0, stream>>>(yl, yr, bl2, csr, rs, invd, out, N);
}

// Round 3
// 359.090 us; speedup vs baseline: 2.5212x; 1.3243x over previous
//
#include <hip/hip_runtime.h>
#include <hip/hip_bf16.h>

// -------------------------------------------------------------------------
// SAGEConv encoder, 2 layers.
// Identity: mean_agg(x) @ Wl^T == mean_agg(x @ Wl^T)  (linearity).
// Per layer:
//   1) MFMA GEMM: y_l = x@Wl^T (bf16 out), y_r = x@Wr^T (bf16 out)
//   2) fused gather-mean(y_l) + y_r + bias + L2-normalize
// CSR built once via 2-level binning (256 buckets of 512 nodes) so all
// scatter writes land in L2-resident per-workgroup windows.
// -------------------------------------------------------------------------

typedef __attribute__((ext_vector_type(8))) short bf16x8;
typedef __attribute__((ext_vector_type(4))) float f32x4;

__device__ __forceinline__ ushort f2bf(float f) {
    uint u = __float_as_uint(f);
    uint r = (u + 0x7FFFu + ((u >> 16) & 1u)) >> 16;   // RNE
    return (ushort)r;
}
__device__ __forceinline__ float bflo(uint u) { return __uint_as_float(u << 16); }
__device__ __forceinline__ float bfhi(uint u) { return __uint_as_float(u & 0xFFFF0000u); }

// ---- edge_index dtype detection (int32 vs int64) -------------------------
__global__ void detect_kernel(const int* __restrict__ ei, int* __restrict__ flag) {
    if (threadIdx.x == 0 && blockIdx.x == 0) {
        int z = 1;
        for (int j = 0; j < 64; ++j)
            if (ei[2 * j + 1] != 0) { z = 0; break; }
        *flag = z;  // 1 -> int64, 0 -> int32
    }
}

__device__ __forceinline__ int load_idx(const void* ei, int is64, size_t i) {
    return is64 ? (int)((const long long*)ei)[i] : ((const int*)ei)[i];
}

// ---- coarse bucket histogram (bucket = dst>>9, 256 buckets) --------------
__global__ __launch_bounds__(256) void bucket_count_kernel(
    const void* __restrict__ ei, const int* __restrict__ flagp,
    int* __restrict__ bcount, int E) {
    __shared__ int h[256];
    h[threadIdx.x] = 0;
    __syncthreads();
    const int is64 = *flagp;
    for (int i = blockIdx.x * 256 + threadIdx.x; i < E; i += gridDim.x * 256) {
        const int d = load_idx(ei, is64, (size_t)E + i);
        atomicAdd(&h[d >> 9], 1);
    }
    __syncthreads();
    atomicAdd(&bcount[threadIdx.x], h[threadIdx.x]);
}

// ---- 256-entry exclusive scan of bucket counts ---------------------------
__global__ void bucket_scan_kernel(const int* __restrict__ bcount,
                                   int* __restrict__ bbase, int* __restrict__ bcursor) {
    __shared__ int wt[4];
    const int tid = threadIdx.x, lane = tid & 63, wid = tid >> 6;
    const int v = bcount[tid];
    int incl = v;
    for (int d = 1; d < 64; d <<= 1) {
        int up = __shfl_up(incl, d, 64);
        if (lane >= d) incl += up;
    }
    if (lane == 63) wt[wid] = incl;
    __syncthreads();
    int woff = 0;
    for (int w = 0; w < wid; ++w) woff += wt[w];
    const int excl = woff + incl - v;
    bbase[tid] = excl;
    bcursor[tid] = excl;
    if (tid == 255) bbase[256] = woff + incl;   // == E
}

// ---- scatter packed (dstlocal<<17)|src into bucket regions ---------------
__global__ __launch_bounds__(256) void bin_scatter_kernel(
    const void* __restrict__ ei, const int* __restrict__ flagp,
    int* __restrict__ bcursor, uint* __restrict__ pairbuf, int E, int ntiles) {
    __shared__ int cnt[256], pos[256];
    const int tid = threadIdx.x;
    const int is64 = *flagp;
    for (int tile = blockIdx.x; tile < ntiles; tile += gridDim.x) {
        const int base = tile * 2048;
        cnt[tid] = 0;
        __syncthreads();
        int eb[8];
        uint ep[8];
#pragma unroll
        for (int j = 0; j < 8; ++j) {
            const int i = base + tid * 8 + j;
            if (i < E) {
                const int s = load_idx(ei, is64, (size_t)i);
                const int d = load_idx(ei, is64, (size_t)E + i);
                eb[j] = d >> 9;
                ep[j] = ((uint)(d & 511) << 17) | (uint)s;
                atomicAdd(&cnt[eb[j]], 1);
            } else {
                eb[j] = -1;
            }
        }
        __syncthreads();
        pos[tid] = atomicAdd(&bcursor[tid], cnt[tid]);   // reserve range
        __syncthreads();
#pragma unroll
        for (int j = 0; j < 8; ++j) {
            if (eb[j] >= 0) {
                const int p = atomicAdd(&pos[eb[j]], 1);
                pairbuf[p] = ep[j];
            }
        }
    }
}

// ---- per-bucket degree count (LDS) + invd --------------------------------
__global__ __launch_bounds__(256) void bucket_deg_kernel(
    const uint* __restrict__ pairbuf, const int* __restrict__ bbase,
    int* __restrict__ deg, float* __restrict__ invd, int N) {
    __shared__ int dg[512];
    const int tid = threadIdx.x, wg = blockIdx.x;
    dg[tid] = 0;
    dg[tid + 256] = 0;
    __syncthreads();
    const int s = bbase[wg], e = bbase[wg + 1];
    for (int i = s + tid; i < e; i += 256)
        atomicAdd(&dg[pairbuf[i] >> 17], 1);
    __syncthreads();
#pragma unroll
    for (int t = tid; t < 512; t += 256) {
        const int node = wg * 512 + t;
        if (node < N) {
            const int d = dg[t];
            deg[node] = d;
            invd[node] = 1.0f / (float)(d > 1 ? d : 1);
        }
    }
}

// ---- scan over deg[] (3 kernels) -----------------------------------------
__global__ void scan1_kernel(const int* __restrict__ deg, int* __restrict__ partial,
                             int* __restrict__ blksum, int n) {
    __shared__ int wtot[4];
    const int tid = threadIdx.x, lane = tid & 63, wid = tid >> 6;
    const int i = blockIdx.x * 256 + tid;
    int v = (i < n) ? deg[i] : 0;
    int incl = v;
    for (int d = 1; d < 64; d <<= 1) {
        int up = __shfl_up(incl, d, 64);
        if (lane >= d) incl += up;
    }
    if (lane == 63) wtot[wid] = incl;
    __syncthreads();
    int woff = 0;
    for (int w = 0; w < wid; ++w) woff += wtot[w];
    if (i < n) partial[i] = woff + incl - v;
    if (tid == 255) blksum[blockIdx.x] = woff + incl;
}

__global__ void scan2_kernel(const int* __restrict__ blksum, int* __restrict__ blkoff, int nb) {
    __shared__ int wtot[8];
    const int tid = threadIdx.x, lane = tid & 63, wid = tid >> 6;
    int v = (tid < nb) ? blksum[tid] : 0;
    int incl = v;
    for (int d = 1; d < 64; d <<= 1) {
        int up = __shfl_up(incl, d, 64);
        if (lane >= d) incl += up;
    }
    if (lane == 63) wtot[wid] = incl;
    __syncthreads();
    int woff = 0;
    for (int w = 0; w < wid; ++w) woff += wtot[w];
    if (tid < nb) blkoff[tid] = woff + incl - v;
    if (tid == nb - 1) blkoff[nb] = woff + incl;
}

__global__ void scan3_kernel(int* __restrict__ rs, const int* __restrict__ blkoff,
                             int n, int nb) {
    const int i = blockIdx.x * 256 + threadIdx.x;
    if (i < n) rs[i] += blkoff[blockIdx.x];
    if (i == 0) rs[n] = blkoff[nb];
}

// ---- per-bucket CSR fill with LDS cursors --------------------------------
__global__ __launch_bounds__(256) void bucket_fill_kernel(
    const uint* __restrict__ pairbuf, const int* __restrict__ bbase,
    const int* __restrict__ rs, int* __restrict__ csr, int N) {
    __shared__ int cur[512];
    const int tid = threadIdx.x, wg = blockIdx.x;
#pragma unroll
    for (int t = tid; t < 512; t += 256) {
        const int node = wg * 512 + t;
        cur[t] = (node < N) ? rs[node] : 0;
    }
    __syncthreads();
    const int s = bbase[wg], e = bbase[wg + 1];
    for (int i = s + tid; i < e; i += 256) {
        const uint p = pairbuf[i];
        const int pos = atomicAdd(&cur[p >> 17], 1);
        csr[pos] = (int)(p & 0x1FFFFu);
    }
}

// ---- f32 -> bf16 conversion (8 elems/thread) -----------------------------
__global__ void convert_bf16_kernel(const float* __restrict__ in, ushort* __restrict__ out,
                                    long total8) {
    const long i = (long)blockIdx.x * 256 + threadIdx.x;
    if (i >= total8) return;
    const float4 a = ((const float4*)in)[2 * i];
    const float4 b = ((const float4*)in)[2 * i + 1];
    uint4 o;
    o.x = (uint)f2bf(a.x) | ((uint)f2bf(a.y) << 16);
    o.y = (uint)f2bf(a.z) | ((uint)f2bf(a.w) << 16);
    o.z = (uint)f2bf(b.x) | ((uint)f2bf(b.y) << 16);
    o.w = (uint)f2bf(b.z) | ((uint)f2bf(b.w) << 16);
    ((uint4*)out)[i] = o;
}

// ---- pack W into MFMA B-fragment layout ----------------------------------
__global__ void pack_w_kernel(const float* __restrict__ Wl1, const float* __restrict__ Wr1,
                              const float* __restrict__ Wl2, const float* __restrict__ Wr2,
                              ushort* __restrict__ Wp) {
    const int gtid = blockIdx.x * 256 + threadIdx.x;   // [0, 8192)
    if (gtid >= 8192) return;
    const int layer = gtid >> 12;
    const int c16   = gtid & 4095;
    const int s     = c16 >> 10;
    const int t     = (c16 >> 6) & 15;
    const int lane  = c16 & 63;
    const int c     = t * 16 + (lane & 15);
    const int kbase = s * 32 + (lane >> 4) * 8;
    const float* Wl = layer ? Wl2 : Wl1;
    const float* Wr = layer ? Wr2 : Wr1;
    const float* src = (c < 128) ? (Wl + c * 128 + kbase) : (Wr + (c - 128) * 128 + kbase);
    ushort* dst = Wp + (size_t)layer * 32768 + (size_t)c16 * 8;
#pragma unroll
    for (int j = 0; j < 8; ++j) dst[j] = f2bf(src[j]);
}

// ---- MFMA GEMM: [n][128]bf16 @ W[256][128]^T -> yl[n][128], yr[n][128] ---
__global__ __launch_bounds__(256) void sage_mfma_gemm(
    const ushort* __restrict__ A, const ushort* __restrict__ Wp,
    ushort* __restrict__ yl, ushort* __restrict__ yr, int n, int mtiles) {
    __shared__ ushort Wlds[32768];
    for (int i = threadIdx.x; i < 4096; i += 256)
        *(bf16x8*)&Wlds[(size_t)i * 8] = *(const bf16x8*)&Wp[(size_t)i * 8];
    __syncthreads();

    const int wid = threadIdx.x >> 6, lane = threadIdx.x & 63;
    const int koff = (lane >> 4) * 8;
    const int rsub = lane & 15;

    int mt = blockIdx.x;
    if (mt >= mtiles) return;

    bf16x8 a_cur[4], a_nxt[4];
    {
        int arow = mt * 64 + wid * 16 + rsub;
        if (arow >= n) arow = 0;
        const ushort* ap = A + ((size_t)arow << 7) + koff;
#pragma unroll
        for (int s = 0; s < 4; ++s) a_cur[s] = *(const bf16x8*)(ap + s * 32);
    }

    while (true) {
        const int mtn = mt + gridDim.x;
        if (mtn < mtiles) {
            int arow = mtn * 64 + wid * 16 + rsub;
            if (arow >= n) arow = 0;
            const ushort* ap = A + ((size_t)arow << 7) + koff;
#pragma unroll
            for (int s = 0; s < 4; ++s) a_nxt[s] = *(const bf16x8*)(ap + s * 32);
        }

        f32x4 acc[16];
        const f32x4 zero = {0.f, 0.f, 0.f, 0.f};
#pragma unroll
        for (int t = 0; t < 16; ++t) acc[t] = zero;

#pragma unroll
        for (int s = 0; s < 4; ++s) {
            const bf16x8 as = a_cur[s];
#pragma unroll
            for (int t = 0; t < 16; ++t) {
                const bf16x8 b = *(const bf16x8*)&Wlds[(size_t)((s * 16 + t) * 64 + lane) * 8];
                acc[t] = __builtin_amdgcn_mfma_f32_16x16x32_bf16(as, b, acc[t], 0, 0, 0);
            }
        }

        const int rowb = mt * 64 + wid * 16 + (lane >> 4) * 4;
#pragma unroll
        for (int t = 0; t < 16; ++t) {
            ushort* dst = (t < 8) ? yl : yr;
            const int col = (t & 7) * 16 + (lane & 15);
#pragma unroll
            for (int r = 0; r < 4; ++r) {
                const int row = rowb + r;
                if (row < n) dst[((size_t)row << 7) + col] = f2bf(acc[t][r]);
            }
        }

        if (mtn >= mtiles) break;
        mt = mtn;
#pragma unroll
        for (int s = 0; s < 4; ++s) a_cur[s] = a_nxt[s];
    }
}

// ---- fused gather-mean + y_r + bias + L2-normalize -----------------------
template <int OUTF32>
__global__ void aggregate_norm_kernel(const ushort* __restrict__ yl, const ushort* __restrict__ yr,
                                      const float* __restrict__ bias, const int* __restrict__ csr,
                                      const int* __restrict__ rs, const float* __restrict__ invd,
                                      void* __restrict__ outp, int n) {
    const int wid = threadIdx.x >> 6, lane = threadIdx.x & 63;
    const int node = blockIdx.x * 4 + wid;
    if (node >= n) return;
    const int s = rs[node], e = rs[node + 1];

    float ax = 0.f, ay = 0.f;
    int q = s;
    for (; q + 2 <= e; q += 2) {
        const int s0 = csr[q], s1 = csr[q + 1];
        const uint u0 = *(const uint*)(yl + ((size_t)s0 << 7) + 2 * lane);
        const uint u1 = *(const uint*)(yl + ((size_t)s1 << 7) + 2 * lane);
        ax += bflo(u0) + bflo(u1);
        ay += bfhi(u0) + bfhi(u1);
    }
    if (q < e) {
        const int s0 = csr[q];
        const uint u0 = *(const uint*)(yl + ((size_t)s0 << 7) + 2 * lane);
        ax += bflo(u0);
        ay += bfhi(u0);
    }

    const float iv = invd[node];
    const uint ur = *(const uint*)(yr + ((size_t)node << 7) + 2 * lane);
    const float2 b2 = *(const float2*)(bias + 2 * lane);
    float vx = fmaf(ax, iv, bflo(ur) + b2.x);
    float vy = fmaf(ay, iv, bfhi(ur) + b2.y);

    float ss = fmaf(vx, vx, vy * vy);
    for (int d = 1; d < 64; d <<= 1) ss += __shfl_xor(ss, d, 64);
    const float sc = 1.0f / fmaxf(sqrtf(ss), 1e-12f);
    vx *= sc; vy *= sc;

    if (OUTF32) {
        ((float2*)outp)[((size_t)node << 6) + lane] = make_float2(vx, vy);
    } else {
        const uint o = (uint)f2bf(vx) | ((uint)f2bf(vy) << 16);
        ((uint*)outp)[((size_t)node << 6) + lane] = o;
    }
}

// -------------------------------------------------------------------------
extern "C" void kernel_launch(void* const* d_in, const int* in_sizes, int n_in,
                              void* d_out, int out_size, void* d_ws, size_t ws_size,
                              hipStream_t stream) {
    const float* x   = (const float*)d_in[0];
    const void*  ei  = d_in[1];
    const float* Wl1 = (const float*)d_in[2];
    const float* bl1 = (const float*)d_in[3];
    const float* Wr1 = (const float*)d_in[4];
    const float* Wl2 = (const float*)d_in[5];
    const float* bl2 = (const float*)d_in[6];
    const float* Wr2 = (const float*)d_in[7];
    float* out = (float*)d_out;

    const int N = in_sizes[0] / 128;
    const int E = in_sizes[1] / 2;

    char* wsb = (char*)d_ws;
    size_t off = 0;
    auto alloc = [&](size_t bytes) -> void* {
        void* p = (void*)(wsb + off);
        off += bytes;
        off = (off + 255) & ~(size_t)255;
        return p;
    };

    int*    deg     = (int*)alloc(4 * (size_t)N);
    int*    rs      = (int*)alloc(4 * (size_t)(N + 1));
    float*  invd    = (float*)alloc(4 * (size_t)N);
    int*    blksum  = (int*)alloc(4 * 2048);
    int*    blkoff  = (int*)alloc(4 * 2049);
    int*    flag    = (int*)alloc(256);
    int*    bcount  = (int*)alloc(4 * 256);
    int*    bbase   = (int*)alloc(4 * 257);
    int*    bcursor = (int*)alloc(4 * 256);
    int*    csr     = (int*)alloc(4 * (size_t)E);
    ushort* xb      = (ushort*)alloc((size_t)N * 128 * 2);  // x bf16, reused as h1
    ushort* yl      = (ushort*)alloc((size_t)N * 128 * 2);
    ushort* yr      = (ushort*)alloc((size_t)N * 128 * 2);
    ushort* Wp      = (ushort*)alloc(2 * 32768 * 2);
    uint*   pairbuf = (uint*)yl;   // alias: pairbuf dead before gemm writes yl

    const int nb = (N + 255) / 256;
    const int ab = (N + 3) / 4;
    const int mtiles = (N + 63) / 64;
    const int ntiles = (E + 2047) / 2048;
    const long total8 = (long)N * 128 / 8;
    const int cb = (int)((total8 + 255) / 256);

    // ---- CSR build (2-level binned) ----
    detect_kernel<<<1, 64, 0, stream>>>((const int*)ei, flag);
    hipMemsetAsync(bcount, 0, 4 * 256, stream);
    bucket_count_kernel<<<512, 256, 0, stream>>>(ei, flag, bcount, E);
    bucket_scan_kernel<<<1, 256, 0, stream>>>(bcount, bbase, bcursor);
    bin_scatter_kernel<<<256, 256, 0, stream>>>(ei, flag, bcursor, pairbuf, E, ntiles);
    bucket_deg_kernel<<<256, 256, 0, stream>>>(pairbuf, bbase, deg, invd, N);
    scan1_kernel<<<nb, 256, 0, stream>>>(deg, rs, blksum, N);
    scan2_kernel<<<1, 512, 0, stream>>>(blksum, blkoff, nb);
    scan3_kernel<<<nb, 256, 0, stream>>>(rs, blkoff, N, nb);
    bucket_fill_kernel<<<256, 256, 0, stream>>>(pairbuf, bbase, rs, csr, N);

    // ---- weight packing + x conversion ----
    pack_w_kernel<<<32, 256, 0, stream>>>(Wl1, Wr1, Wl2, Wr2, Wp);
    convert_bf16_kernel<<<cb, 256, 0, stream>>>(x, xb, total8);

    // ---- Layer 1 ----
    sage_mfma_gemm<<<512, 256, 0, stream>>>(xb, Wp, yl, yr, N, mtiles);
    aggregate_norm_kernel<0><<<ab, 256, 0, stream>>>(yl, yr, bl1, csr, rs, invd, xb, N);

    // ---- Layer 2 ----
    sage_mfma_gemm<<<512, 256, 0, stream>>>(xb, Wp + 32768, yl, yr, N, mtiles);
    aggregate_norm_kernel<1><<<ab, 256, 0, stream>>>(yl, yr, bl2, csr, rs, invd, out, N);
}

// Round 4
// 288.326 us; speedup vs baseline: 3.1400x; 1.2454x over previous
//
#include <hip/hip_runtime.h>
#include <hip/hip_bf16.h>

// -------------------------------------------------------------------------
// SAGEConv encoder, 2 layers.
// Identity: mean_agg(x) @ Wl^T == mean_agg(x @ Wl^T)  (linearity).
// Per layer:
//   1) MFMA GEMM: y_l = x@Wl^T (bf16 out), y_r = x@Wr^T (bf16 out)
//   2) fused gather-mean(y_l) + y_r + bias + L2-normalize
//      (16-lane-group gathers: 4 edges per wave-load, 8 edges in flight)
// CSR built once via 2-level binning (256 buckets of 512 nodes).
// -------------------------------------------------------------------------

typedef __attribute__((ext_vector_type(8))) short bf16x8;
typedef __attribute__((ext_vector_type(4))) float f32x4;

__device__ __forceinline__ ushort f2bf(float f) {
    uint u = __float_as_uint(f);
    uint r = (u + 0x7FFFu + ((u >> 16) & 1u)) >> 16;   // RNE
    return (ushort)r;
}
__device__ __forceinline__ float bflo(uint u) { return __uint_as_float(u << 16); }
__device__ __forceinline__ float bfhi(uint u) { return __uint_as_float(u & 0xFFFF0000u); }

// ---- edge_index dtype detection (int32 vs int64) -------------------------
__global__ void detect_kernel(const int* __restrict__ ei, int* __restrict__ flag) {
    if (threadIdx.x == 0 && blockIdx.x == 0) {
        int z = 1;
        for (int j = 0; j < 64; ++j)
            if (ei[2 * j + 1] != 0) { z = 0; break; }
        *flag = z;  // 1 -> int64, 0 -> int32
    }
}

__device__ __forceinline__ int load_idx(const void* ei, int is64, size_t i) {
    return is64 ? (int)((const long long*)ei)[i] : ((const int*)ei)[i];
}

// ---- coarse bucket histogram (bucket = dst>>9, 256 buckets) --------------
__global__ __launch_bounds__(256) void bucket_count_kernel(
    const void* __restrict__ ei, const int* __restrict__ flagp,
    int* __restrict__ bcount, int E) {
    __shared__ int h[256];
    h[threadIdx.x] = 0;
    __syncthreads();
    const int is64 = *flagp;
    for (int i = blockIdx.x * 256 + threadIdx.x; i < E; i += gridDim.x * 256) {
        const int d = load_idx(ei, is64, (size_t)E + i);
        atomicAdd(&h[d >> 9], 1);
    }
    __syncthreads();
    atomicAdd(&bcount[threadIdx.x], h[threadIdx.x]);
}

// ---- 256-entry exclusive scan of bucket counts ---------------------------
__global__ void bucket_scan_kernel(const int* __restrict__ bcount,
                                   int* __restrict__ bbase, int* __restrict__ bcursor) {
    __shared__ int wt[4];
    const int tid = threadIdx.x, lane = tid & 63, wid = tid >> 6;
    const int v = bcount[tid];
    int incl = v;
    for (int d = 1; d < 64; d <<= 1) {
        int up = __shfl_up(incl, d, 64);
        if (lane >= d) incl += up;
    }
    if (lane == 63) wt[wid] = incl;
    __syncthreads();
    int woff = 0;
    for (int w = 0; w < wid; ++w) woff += wt[w];
    const int excl = woff + incl - v;
    bbase[tid] = excl;
    bcursor[tid] = excl;
    if (tid == 255) bbase[256] = woff + incl;   // == E
}

// ---- scatter packed (dstlocal<<17)|src into bucket regions ---------------
__global__ __launch_bounds__(256) void bin_scatter_kernel(
    const void* __restrict__ ei, const int* __restrict__ flagp,
    int* __restrict__ bcursor, uint* __restrict__ pairbuf, int E, int ntiles) {
    __shared__ int cnt[256], pos[256];
    const int tid = threadIdx.x;
    const int is64 = *flagp;
    for (int tile = blockIdx.x; tile < ntiles; tile += gridDim.x) {
        const int base = tile * 2048;
        cnt[tid] = 0;
        __syncthreads();
        int eb[8];
        uint ep[8];
#pragma unroll
        for (int j = 0; j < 8; ++j) {
            const int i = base + tid * 8 + j;
            if (i < E) {
                const int s = load_idx(ei, is64, (size_t)i);
                const int d = load_idx(ei, is64, (size_t)E + i);
                eb[j] = d >> 9;
                ep[j] = ((uint)(d & 511) << 17) | (uint)s;
                atomicAdd(&cnt[eb[j]], 1);
            } else {
                eb[j] = -1;
            }
        }
        __syncthreads();
        pos[tid] = atomicAdd(&bcursor[tid], cnt[tid]);   // reserve range
        __syncthreads();
#pragma unroll
        for (int j = 0; j < 8; ++j) {
            if (eb[j] >= 0) {
                const int p = atomicAdd(&pos[eb[j]], 1);
                pairbuf[p] = ep[j];
            }
        }
    }
}

// ---- per-bucket degree count (LDS) + invd --------------------------------
__global__ __launch_bounds__(256) void bucket_deg_kernel(
    const uint* __restrict__ pairbuf, const int* __restrict__ bbase,
    int* __restrict__ deg, float* __restrict__ invd, int N) {
    __shared__ int dg[512];
    const int tid = threadIdx.x, wg = blockIdx.x;
    dg[tid] = 0;
    dg[tid + 256] = 0;
    __syncthreads();
    const int s = bbase[wg], e = bbase[wg + 1];
    for (int i = s + tid; i < e; i += 256)
        atomicAdd(&dg[pairbuf[i] >> 17], 1);
    __syncthreads();
#pragma unroll
    for (int t = tid; t < 512; t += 256) {
        const int node = wg * 512 + t;
        if (node < N) {
            const int d = dg[t];
            deg[node] = d;
            invd[node] = 1.0f / (float)(d > 1 ? d : 1);
        }
    }
}

// ---- scan over deg[] (3 kernels) -----------------------------------------
__global__ void scan1_kernel(const int* __restrict__ deg, int* __restrict__ partial,
                             int* __restrict__ blksum, int n) {
    __shared__ int wtot[4];
    const int tid = threadIdx.x, lane = tid & 63, wid = tid >> 6;
    const int i = blockIdx.x * 256 + tid;
    int v = (i < n) ? deg[i] : 0;
    int incl = v;
    for (int d = 1; d < 64; d <<= 1) {
        int up = __shfl_up(incl, d, 64);
        if (lane >= d) incl += up;
    }
    if (lane == 63) wtot[wid] = incl;
    __syncthreads();
    int woff = 0;
    for (int w = 0; w < wid; ++w) woff += wtot[w];
    if (i < n) partial[i] = woff + incl - v;
    if (tid == 255) blksum[blockIdx.x] = woff + incl;
}

__global__ void scan2_kernel(const int* __restrict__ blksum, int* __restrict__ blkoff, int nb) {
    __shared__ int wtot[8];
    const int tid = threadIdx.x, lane = tid & 63, wid = tid >> 6;
    int v = (tid < nb) ? blksum[tid] : 0;
    int incl = v;
    for (int d = 1; d < 64; d <<= 1) {
        int up = __shfl_up(incl, d, 64);
        if (lane >= d) incl += up;
    }
    if (lane == 63) wtot[wid] = incl;
    __syncthreads();
    int woff = 0;
    for (int w = 0; w < wid; ++w) woff += wtot[w];
    if (tid < nb) blkoff[tid] = woff + incl - v;
    if (tid == nb - 1) blkoff[nb] = woff + incl;
}

__global__ void scan3_kernel(int* __restrict__ rs, const int* __restrict__ blkoff,
                             int n, int nb) {
    const int i = blockIdx.x * 256 + threadIdx.x;
    if (i < n) rs[i] += blkoff[blockIdx.x];
    if (i == 0) rs[n] = blkoff[nb];
}

// ---- per-bucket CSR fill with LDS cursors --------------------------------
__global__ __launch_bounds__(256) void bucket_fill_kernel(
    const uint* __restrict__ pairbuf, const int* __restrict__ bbase,
    const int* __restrict__ rs, int* __restrict__ csr, int N) {
    __shared__ int cur[512];
    const int tid = threadIdx.x, wg = blockIdx.x;
#pragma unroll
    for (int t = tid; t < 512; t += 256) {
        const int node = wg * 512 + t;
        cur[t] = (node < N) ? rs[node] : 0;
    }
    __syncthreads();
    const int s = bbase[wg], e = bbase[wg + 1];
    for (int i = s + tid; i < e; i += 256) {
        const uint p = pairbuf[i];
        const int pos = atomicAdd(&cur[p >> 17], 1);
        csr[pos] = (int)(p & 0x1FFFFu);
    }
}

// ---- f32 -> bf16 conversion (8 elems/thread) -----------------------------
__global__ void convert_bf16_kernel(const float* __restrict__ in, ushort* __restrict__ out,
                                    long total8) {
    const long i = (long)blockIdx.x * 256 + threadIdx.x;
    if (i >= total8) return;
    const float4 a = ((const float4*)in)[2 * i];
    const float4 b = ((const float4*)in)[2 * i + 1];
    uint4 o;
    o.x = (uint)f2bf(a.x) | ((uint)f2bf(a.y) << 16);
    o.y = (uint)f2bf(a.z) | ((uint)f2bf(a.w) << 16);
    o.z = (uint)f2bf(b.x) | ((uint)f2bf(b.y) << 16);
    o.w = (uint)f2bf(b.z) | ((uint)f2bf(b.w) << 16);
    ((uint4*)out)[i] = o;
}

// ---- pack W into MFMA B-fragment layout ----------------------------------
__global__ void pack_w_kernel(const float* __restrict__ Wl1, const float* __restrict__ Wr1,
                              const float* __restrict__ Wl2, const float* __restrict__ Wr2,
                              ushort* __restrict__ Wp) {
    const int gtid = blockIdx.x * 256 + threadIdx.x;   // [0, 8192)
    if (gtid >= 8192) return;
    const int layer = gtid >> 12;
    const int c16   = gtid & 4095;
    const int s     = c16 >> 10;
    const int t     = (c16 >> 6) & 15;
    const int lane  = c16 & 63;
    const int c     = t * 16 + (lane & 15);
    const int kbase = s * 32 + (lane >> 4) * 8;
    const float* Wl = layer ? Wl2 : Wl1;
    const float* Wr = layer ? Wr2 : Wr1;
    const float* src = (c < 128) ? (Wl + c * 128 + kbase) : (Wr + (c - 128) * 128 + kbase);
    ushort* dst = Wp + (size_t)layer * 32768 + (size_t)c16 * 8;
#pragma unroll
    for (int j = 0; j < 8; ++j) dst[j] = f2bf(src[j]);
}

// ---- MFMA GEMM: [n][128]bf16 @ W[256][128]^T -> yl[n][128], yr[n][128] ---
__global__ __launch_bounds__(256) void sage_mfma_gemm(
    const ushort* __restrict__ A, const ushort* __restrict__ Wp,
    ushort* __restrict__ yl, ushort* __restrict__ yr, int n, int mtiles) {
    __shared__ ushort Wlds[32768];
    for (int i = threadIdx.x; i < 4096; i += 256)
        *(bf16x8*)&Wlds[(size_t)i * 8] = *(const bf16x8*)&Wp[(size_t)i * 8];
    __syncthreads();

    const int wid = threadIdx.x >> 6, lane = threadIdx.x & 63;
    const int koff = (lane >> 4) * 8;
    const int rsub = lane & 15;

    int mt = blockIdx.x;
    if (mt >= mtiles) return;

    bf16x8 a_cur[4], a_nxt[4];
    {
        int arow = mt * 64 + wid * 16 + rsub;
        if (arow >= n) arow = 0;
        const ushort* ap = A + ((size_t)arow << 7) + koff;
#pragma unroll
        for (int s = 0; s < 4; ++s) a_cur[s] = *(const bf16x8*)(ap + s * 32);
    }

    while (true) {
        const int mtn = mt + gridDim.x;
        if (mtn < mtiles) {
            int arow = mtn * 64 + wid * 16 + rsub;
            if (arow >= n) arow = 0;
            const ushort* ap = A + ((size_t)arow << 7) + koff;
#pragma unroll
            for (int s = 0; s < 4; ++s) a_nxt[s] = *(const bf16x8*)(ap + s * 32);
        }

        f32x4 acc[16];
        const f32x4 zero = {0.f, 0.f, 0.f, 0.f};
#pragma unroll
        for (int t = 0; t < 16; ++t) acc[t] = zero;

#pragma unroll
        for (int s = 0; s < 4; ++s) {
            const bf16x8 as = a_cur[s];
#pragma unroll
            for (int t = 0; t < 16; ++t) {
                const bf16x8 b = *(const bf16x8*)&Wlds[(size_t)((s * 16 + t) * 64 + lane) * 8];
                acc[t] = __builtin_amdgcn_mfma_f32_16x16x32_bf16(as, b, acc[t], 0, 0, 0);
            }
        }

        const int rowb = mt * 64 + wid * 16 + (lane >> 4) * 4;
#pragma unroll
        for (int t = 0; t < 16; ++t) {
            ushort* dst = (t < 8) ? yl : yr;
            const int col = (t & 7) * 16 + (lane & 15);
#pragma unroll
            for (int r = 0; r < 4; ++r) {
                const int row = rowb + r;
                if (row < n) dst[((size_t)row << 7) + col] = f2bf(acc[t][r]);
            }
        }

        if (mtn >= mtiles) break;
        mt = mtn;
#pragma unroll
        for (int s = 0; s < 4; ++s) a_cur[s] = a_nxt[s];
    }
}

// ---- fused gather-mean + y_r + bias + L2-normalize -----------------------
// One wave per node. 4 groups of 16 lanes; group g gathers edge q=s+g+4i,
// lane t loads uint4 (channels 8t..8t+7). 4 edges per wave-load, unroll 2.
template <int OUTF32>
__global__ __launch_bounds__(256) void aggregate_norm_kernel(
    const ushort* __restrict__ yl, const ushort* __restrict__ yr,
    const float* __restrict__ bias, const int* __restrict__ csr,
    const int* __restrict__ rs, const float* __restrict__ invd,
    void* __restrict__ outp, int n) {
    const int wid = threadIdx.x >> 6, lane = threadIdx.x & 63;
    const int node = blockIdx.x * 4 + wid;
    if (node >= n) return;
    const int g = lane >> 4, t = lane & 15;
    const int s = rs[node], e = rs[node + 1];

    float ax[8];
#pragma unroll
    for (int j = 0; j < 8; ++j) ax[j] = 0.f;

    int q = s + g;
    for (; q + 4 < e; q += 8) {
        const int s0 = csr[q], s1 = csr[q + 4];
        const uint4 u0 = *(const uint4*)(yl + ((size_t)s0 << 7) + 8 * t);
        const uint4 u1 = *(const uint4*)(yl + ((size_t)s1 << 7) + 8 * t);
        ax[0] += bflo(u0.x) + bflo(u1.x);
        ax[1] += bfhi(u0.x) + bfhi(u1.x);
        ax[2] += bflo(u0.y) + bflo(u1.y);
        ax[3] += bfhi(u0.y) + bfhi(u1.y);
        ax[4] += bflo(u0.z) + bflo(u1.z);
        ax[5] += bfhi(u0.z) + bfhi(u1.z);
        ax[6] += bflo(u0.w) + bflo(u1.w);
        ax[7] += bfhi(u0.w) + bfhi(u1.w);
    }
    if (q < e) {
        const int s0 = csr[q];
        const uint4 u0 = *(const uint4*)(yl + ((size_t)s0 << 7) + 8 * t);
        ax[0] += bflo(u0.x); ax[1] += bfhi(u0.x);
        ax[2] += bflo(u0.y); ax[3] += bfhi(u0.y);
        ax[4] += bflo(u0.z); ax[5] += bfhi(u0.z);
        ax[6] += bflo(u0.w); ax[7] += bfhi(u0.w);
    }

    // fold the 4 group-partials (lanes ^16, ^32)
#pragma unroll
    for (int j = 0; j < 8; ++j) {
        ax[j] += __shfl_xor(ax[j], 16, 64);
        ax[j] += __shfl_xor(ax[j], 32, 64);
    }

    const float iv = invd[node];
    const uint4 ur = *(const uint4*)(yr + ((size_t)node << 7) + 8 * t);
    const float4 b0 = *(const float4*)(bias + 8 * t);
    const float4 b1 = *(const float4*)(bias + 8 * t + 4);
    float v[8];
    v[0] = fmaf(ax[0], iv, bflo(ur.x) + b0.x);
    v[1] = fmaf(ax[1], iv, bfhi(ur.x) + b0.y);
    v[2] = fmaf(ax[2], iv, bflo(ur.y) + b0.z);
    v[3] = fmaf(ax[3], iv, bfhi(ur.y) + b0.w);
    v[4] = fmaf(ax[4], iv, bflo(ur.z) + b1.x);
    v[5] = fmaf(ax[5], iv, bfhi(ur.z) + b1.y);
    v[6] = fmaf(ax[6], iv, bflo(ur.w) + b1.z);
    v[7] = fmaf(ax[7], iv, bfhi(ur.w) + b1.w);

    float ss = 0.f;
#pragma unroll
    for (int j = 0; j < 8; ++j) ss = fmaf(v[j], v[j], ss);
    ss += __shfl_xor(ss, 1, 64);
    ss += __shfl_xor(ss, 2, 64);
    ss += __shfl_xor(ss, 4, 64);
    ss += __shfl_xor(ss, 8, 64);
    const float sc = 1.0f / fmaxf(sqrtf(ss), 1e-12f);

    if (g == 0) {
        if (OUTF32) {
            float4 o0 = {v[0] * sc, v[1] * sc, v[2] * sc, v[3] * sc};
            float4 o1 = {v[4] * sc, v[5] * sc, v[6] * sc, v[7] * sc};
            ((float4*)outp)[((size_t)node << 5) + 2 * t]     = o0;
            ((float4*)outp)[((size_t)node << 5) + 2 * t + 1] = o1;
        } else {
            uint4 o;
            o.x = (uint)f2bf(v[0] * sc) | ((uint)f2bf(v[1] * sc) << 16);
            o.y = (uint)f2bf(v[2] * sc) | ((uint)f2bf(v[3] * sc) << 16);
            o.z = (uint)f2bf(v[4] * sc) | ((uint)f2bf(v[5] * sc) << 16);
            o.w = (uint)f2bf(v[6] * sc) | ((uint)f2bf(v[7] * sc) << 16);
            ((uint4*)outp)[((size_t)node << 4) + t] = o;
        }
    }
}

// -------------------------------------------------------------------------
extern "C" void kernel_launch(void* const* d_in, const int* in_sizes, int n_in,
                              void* d_out, int out_size, void* d_ws, size_t ws_size,
                              hipStream_t stream) {
    const float* x   = (const float*)d_in[0];
    const void*  ei  = d_in[1];
    const float* Wl1 = (const float*)d_in[2];
    const float* bl1 = (const float*)d_in[3];
    const float* Wr1 = (const float*)d_in[4];
    const float* Wl2 = (const float*)d_in[5];
    const float* bl2 = (const float*)d_in[6];
    const float* Wr2 = (const float*)d_in[7];
    float* out = (float*)d_out;

    const int N = in_sizes[0] / 128;
    const int E = in_sizes[1] / 2;

    char* wsb = (char*)d_ws;
    size_t off = 0;
    auto alloc = [&](size_t bytes) -> void* {
        void* p = (void*)(wsb + off);
        off += bytes;
        off = (off + 255) & ~(size_t)255;
        return p;
    };

    int*    deg     = (int*)alloc(4 * (size_t)N);
    int*    rs      = (int*)alloc(4 * (size_t)(N + 1));
    float*  invd    = (float*)alloc(4 * (size_t)N);
    int*    blksum  = (int*)alloc(4 * 2048);
    int*    blkoff  = (int*)alloc(4 * 2049);
    int*    flag    = (int*)alloc(256);
    int*    bcount  = (int*)alloc(4 * 256);
    int*    bbase   = (int*)alloc(4 * 257);
    int*    bcursor = (int*)alloc(4 * 256);
    int*    csr     = (int*)alloc(4 * (size_t)E);
    ushort* xb      = (ushort*)alloc((size_t)N * 128 * 2);  // x bf16, reused as h1
    ushort* yl      = (ushort*)alloc((size_t)N * 128 * 2);
    ushort* yr      = (ushort*)alloc((size_t)N * 128 * 2);
    ushort* Wp      = (ushort*)alloc(2 * 32768 * 2);
    uint*   pairbuf = (uint*)yl;   // alias: pairbuf dead before gemm writes yl

    const int nb = (N + 255) / 256;
    const int ab = (N + 3) / 4;
    const int mtiles = (N + 63) / 64;
    const int ntiles = (E + 2047) / 2048;
    const long total8 = (long)N * 128 / 8;
    const int cb = (int)((total8 + 255) / 256);

    // ---- CSR build (2-level binned) ----
    detect_kernel<<<1, 64, 0, stream>>>((const int*)ei, flag);
    hipMemsetAsync(bcount, 0, 4 * 256, stream);
    bucket_count_kernel<<<512, 256, 0, stream>>>(ei, flag, bcount, E);
    bucket_scan_kernel<<<1, 256, 0, stream>>>(bcount, bbase, bcursor);
    bin_scatter_kernel<<<256, 256, 0, stream>>>(ei, flag, bcursor, pairbuf, E, ntiles);
    bucket_deg_kernel<<<256, 256, 0, stream>>>(pairbuf, bbase, deg, invd, N);
    scan1_kernel<<<nb, 256, 0, stream>>>(deg, rs, blksum, N);
    scan2_kernel<<<1, 512, 0, stream>>>(blksum, blkoff, nb);
    scan3_kernel<<<nb, 256, 0, stream>>>(rs, blkoff, N, nb);
    bucket_fill_kernel<<<256, 256, 0, stream>>>(pairbuf, bbase, rs, csr, N);

    // ---- weight packing + x conversion ----
    pack_w_kernel<<<32, 256, 0, stream>>>(Wl1, Wr1, Wl2, Wr2, Wp);
    convert_bf16_kernel<<<cb, 256, 0, stream>>>(x, xb, total8);

    // ---- Layer 1 ----
    sage_mfma_gemm<<<512, 256, 0, stream>>>(xb, Wp, yl, yr, N, mtiles);
    aggregate_norm_kernel<0><<<ab, 256, 0, stream>>>(yl, yr, bl1, csr, rs, invd, xb, N);

    // ---- Layer 2 ----
    sage_mfma_gemm<<<512, 256, 0, stream>>>(xb, Wp + 32768, yl, yr, N, mtiles);
    aggregate_norm_kernel<1><<<ab, 256, 0, stream>>>(yl, yr, bl2, csr, rs, invd, out, N);
}